// Round 4
// baseline (70.559 us; speedup 1.0000x reference)
//
#include <hip/hip_runtime.h>

// SumFunc: per-row softmax(d1), softmax(d2) over 10 logits, full 1-D conv -> 19 outs.
// B = 2,097,152 rows, fp32. Memory-bound: 327 MB @ ~6.3 TB/s achievable => ~52 us floor.
//
// R4: R3 retry — nontemporal builtins need clang ext_vector_type, not
// HIP_vector_type classes. NT hints on all global loads/stores to avoid
// L2/L3 write-allocate + eviction thrash (3 zero-reuse streams > 256 MB L3).

constexpr int D   = 10;
constexpr int S   = 19;
constexpr int BLK = 256;

typedef float vf2 __attribute__((ext_vector_type(2)));
typedef float vf4 __attribute__((ext_vector_type(4)));

__global__ __launch_bounds__(BLK) void sumfunc_kernel(
    const float* __restrict__ d1, const float* __restrict__ d2,
    float* __restrict__ out, int n)
{
    __shared__ float so[BLK * S];   // 19 KiB -> 8 blocks/CU

    const int tid = threadIdx.x;
    const long long blockStart = (long long)blockIdx.x * BLK;
    const long long row = blockStart + tid;
    const bool fullBlock = (blockStart + BLK) <= n;

    if (row < n) {
        // Direct row loads, non-temporal (row*40 B is 8-aligned).
        const vf2* p1 = reinterpret_cast<const vf2*>(d1 + row * D);
        const vf2* p2 = reinterpret_cast<const vf2*>(d2 + row * D);
        float a[D], b[D];
        #pragma unroll
        for (int i = 0; i < 5; ++i) {
            vf2 v1 = __builtin_nontemporal_load(&p1[i]);
            vf2 v2 = __builtin_nontemporal_load(&p2[i]);
            a[2*i] = v1.x; a[2*i+1] = v1.y;
            b[2*i] = v2.x; b[2*i+1] = v2.y;
        }

        // Stable unnormalized softmax numerators; single normalize at the end.
        float m1 = a[0], m2 = b[0];
        #pragma unroll
        for (int i = 1; i < D; ++i) { m1 = fmaxf(m1, a[i]); m2 = fmaxf(m2, b[i]); }
        float s1 = 0.f, s2 = 0.f;
        #pragma unroll
        for (int i = 0; i < D; ++i) {
            a[i] = __expf(a[i] - m1); s1 += a[i];
            b[i] = __expf(b[i] - m2); s2 += b[i];
        }
        const float inv = 1.0f / (s1 * s2);

        // 10x10 full convolution (100 FMAs).
        float c[S];
        #pragma unroll
        for (int k = 0; k < S; ++k) c[k] = 0.f;
        #pragma unroll
        for (int i = 0; i < D; ++i) {
            #pragma unroll
            for (int j = 0; j < D; ++j) c[i + j] = fmaf(a[i], b[j], c[i + j]);
        }

        // Stage in LDS: stride-19 (odd) writes -> benign 2-way aliasing.
        #pragma unroll
        for (int k = 0; k < S; ++k) so[tid * S + k] = c[k] * inv;
    }
    __syncthreads();

    if (fullBlock) {
        // Flat float4 non-temporal stores: 1216 per block.
        const vf4* lo = reinterpret_cast<const vf4*>(so);
        vf4* go = reinterpret_cast<vf4*>(out + blockStart * S);
        __builtin_nontemporal_store(lo[tid],       &go[tid]);
        __builtin_nontemporal_store(lo[tid + 256], &go[tid + 256]);
        __builtin_nontemporal_store(lo[tid + 512], &go[tid + 512]);
        __builtin_nontemporal_store(lo[tid + 768], &go[tid + 768]);
        if (tid < 192)
            __builtin_nontemporal_store(lo[tid + 1024], &go[tid + 1024]);
    } else if (row < n) {
        float* po = out + row * S;
        #pragma unroll
        for (int k = 0; k < S; ++k)
            __builtin_nontemporal_store(so[tid * S + k], &po[k]);
    }
}

extern "C" void kernel_launch(void* const* d_in, const int* in_sizes, int n_in,
                              void* d_out, int out_size, void* d_ws, size_t ws_size,
                              hipStream_t stream) {
    const float* d1 = (const float*)d_in[0];
    const float* d2 = (const float*)d_in[1];
    float* out = (float*)d_out;
    const int n = in_sizes[0] / D;
    const int grid = (n + BLK - 1) / BLK;
    sumfunc_kernel<<<grid, BLK, 0, stream>>>(d1, d2, out, n);
}

// Round 5
// 51.845 us; speedup vs baseline: 1.3609x; 1.3609x over previous
//
#include <hip/hip_runtime.h>

// SumFunc: per-row softmax(d1), softmax(d2) over 10 logits, full 1-D conv -> 19 outs.
// B = 2,097,152 rows, fp32. Memory-bound.
//
// R5: asymmetric cache hints — CACHED loads (inputs are 168 MB < 256 MB L3 and
// stay resident across timed replays; R2 profile showed FETCH 84 MB << 168 MB),
// NON-TEMPORAL stores (write-once 159 MB stream is what evicts the inputs).
// R4 showed NT loads defeat L3 residency (62->70.6 us). Structure otherwise = R1
// (direct float2 row loads; output through LDS for flat float4 stores).

constexpr int D   = 10;
constexpr int S   = 19;
constexpr int BLK = 256;

typedef float vf4 __attribute__((ext_vector_type(4)));

__global__ __launch_bounds__(BLK) void sumfunc_kernel(
    const float* __restrict__ d1, const float* __restrict__ d2,
    float* __restrict__ out, int n)
{
    __shared__ float so[BLK * S];   // 19 KiB -> 8 blocks/CU

    const int tid = threadIdx.x;
    const long long blockStart = (long long)blockIdx.x * BLK;
    const long long row = blockStart + tid;
    const bool fullBlock = (blockStart + BLK) <= n;

    if (row < n) {
        // Direct cached row loads (row*40 B is 8-aligned).
        const float2* p1 = reinterpret_cast<const float2*>(d1 + row * D);
        const float2* p2 = reinterpret_cast<const float2*>(d2 + row * D);
        float a[D], b[D];
        #pragma unroll
        for (int i = 0; i < 5; ++i) {
            float2 v1 = p1[i];
            float2 v2 = p2[i];
            a[2*i] = v1.x; a[2*i+1] = v1.y;
            b[2*i] = v2.x; b[2*i+1] = v2.y;
        }

        // Stable unnormalized softmax numerators; single normalize at the end.
        float m1 = a[0], m2 = b[0];
        #pragma unroll
        for (int i = 1; i < D; ++i) { m1 = fmaxf(m1, a[i]); m2 = fmaxf(m2, b[i]); }
        float s1 = 0.f, s2 = 0.f;
        #pragma unroll
        for (int i = 0; i < D; ++i) {
            a[i] = __expf(a[i] - m1); s1 += a[i];
            b[i] = __expf(b[i] - m2); s2 += b[i];
        }
        const float inv = 1.0f / (s1 * s2);

        // 10x10 full convolution (100 FMAs).
        float c[S];
        #pragma unroll
        for (int k = 0; k < S; ++k) c[k] = 0.f;
        #pragma unroll
        for (int i = 0; i < D; ++i) {
            #pragma unroll
            for (int j = 0; j < D; ++j) c[i + j] = fmaf(a[i], b[j], c[i + j]);
        }

        // Stage in LDS: stride-19 (odd) writes -> benign 2-way aliasing.
        #pragma unroll
        for (int k = 0; k < S; ++k) so[tid * S + k] = c[k] * inv;
    }
    __syncthreads();

    if (fullBlock) {
        // Flat float4 NON-TEMPORAL stores: 1216 per block (streams past L2/L3).
        const vf4* lo = reinterpret_cast<const vf4*>(so);
        vf4* go = reinterpret_cast<vf4*>(out + blockStart * S);
        __builtin_nontemporal_store(lo[tid],       &go[tid]);
        __builtin_nontemporal_store(lo[tid + 256], &go[tid + 256]);
        __builtin_nontemporal_store(lo[tid + 512], &go[tid + 512]);
        __builtin_nontemporal_store(lo[tid + 768], &go[tid + 768]);
        if (tid < 192)
            __builtin_nontemporal_store(lo[tid + 1024], &go[tid + 1024]);
    } else if (row < n) {
        float* po = out + row * S;
        #pragma unroll
        for (int k = 0; k < S; ++k)
            __builtin_nontemporal_store(so[tid * S + k], &po[k]);
    }
}

extern "C" void kernel_launch(void* const* d_in, const int* in_sizes, int n_in,
                              void* d_out, int out_size, void* d_ws, size_t ws_size,
                              hipStream_t stream) {
    const float* d1 = (const float*)d_in[0];
    const float* d2 = (const float*)d_in[1];
    float* out = (float*)d_out;
    const int n = in_sizes[0] / D;
    const int grid = (n + BLK - 1) / BLK;
    sumfunc_kernel<<<grid, BLK, 0, stream>>>(d1, d2, out, n);
}